// Round 11
// baseline (25095.705 us; speedup 1.0000x reference)
//
#include <hip/hip_runtime.h>

typedef float f2 __attribute__((ext_vector_type(2)));
typedef unsigned u2v __attribute__((ext_vector_type(2)));

// ---- XOR-butterfly reduction, all-VALU (proven bit-uniform, R5-R10) -----
template<int CTRL>
__device__ __forceinline__ float dpp_xadd(float v) {
    int s = __builtin_amdgcn_update_dpp(0, __float_as_int(v), CTRL, 0xF, 0xF, true);
    return v + __int_as_float(s);
}

#if __has_builtin(__builtin_amdgcn_permlane16_swap)
__device__ __forceinline__ float xor16_add(float v) {
    u2v r = __builtin_amdgcn_permlane16_swap((unsigned)__float_as_int(v),
                                             (unsigned)__float_as_int(v),
                                             false, false);
    return __int_as_float((int)r.x) + __int_as_float((int)r.y);
}
#else
__device__ __forceinline__ float xor16_add(float v) {
    int s = __builtin_amdgcn_ds_swizzle(__float_as_int(v), 0x401F);
    return v + __int_as_float(s);
}
#endif

__device__ __forceinline__ float red32(float v) {
    v = dpp_xadd<0xB1>(v);    // lane ^ 1
    v = dpp_xadd<0x4E>(v);    // lane ^ 2
    v = dpp_xadd<0x141>(v);   // lane ^ 7
    v = dpp_xadd<0x140>(v);   // lane ^ 15
    v = xor16_add(v);         // lane ^ 16
    return v;
}

// ---- VOP3P packed complex helpers ---------------------------------------
// f2 = (re, im) in (lo, hi) of an even-aligned VGPR pair. Each pk op is two
// independent IEEE f32 ops -> same numerics class as the scalar versions.

// r = a*b:  r.lo = ar*br - ai*bi ; r.hi = ar*bi + ai*br
__device__ __forceinline__ f2 cmul(f2 a, f2 b) {
    f2 t, r;
    // t.lo = a.lo*b.lo ; t.hi = a.lo*b.hi   (src0 hi<-lo)
    asm("v_pk_mul_f32 %0, %1, %2 op_sel_hi:[0,1]" : "=v"(t) : "v"(a), "v"(b));
    // r.lo = (-a.hi)*b.hi + t.lo ; r.hi = a.hi*b.lo + t.hi
    asm("v_pk_fma_f32 %0, %1, %2, %3 op_sel:[1,1,0] op_sel_hi:[1,0,1] neg_lo:[1,0,0]"
        : "=v"(r) : "v"(a), "v"(b), "v"(t));
    return r;
}

// r = a*conj(b):  r.lo = ar*br + ai*bi ; r.hi = ai*br - ar*bi
__device__ __forceinline__ f2 cmulc(f2 a, f2 b) {
    f2 t, r;
    // t.lo = a.lo*b.lo ; t.hi = a.hi*b.lo   (src1 hi<-lo)
    asm("v_pk_mul_f32 %0, %1, %2 op_sel_hi:[1,0]" : "=v"(t) : "v"(a), "v"(b));
    // r.lo = a.hi*b.hi + t.lo ; r.hi = (-a.lo)*b.hi + t.hi
    asm("v_pk_fma_f32 %0, %1, %2, %3 op_sel:[1,1,0] op_sel_hi:[0,1,1] neg_hi:[1,0,0]"
        : "=v"(r) : "v"(a), "v"(b), "v"(t));
    return r;
}

// acc += a*b (complex accumulate), same association as scalar R10 code
__device__ __forceinline__ f2 cfma(f2 a, f2 b, f2 acc) {
    f2 t, r;
    // t.lo = a.lo*b.lo + acc.lo ; t.hi = a.lo*b.hi + acc.hi
    asm("v_pk_fma_f32 %0, %1, %2, %3 op_sel_hi:[0,1,1]"
        : "=v"(t) : "v"(a), "v"(b), "v"(acc));
    // r.lo = (-a.hi)*b.hi + t.lo ; r.hi = a.hi*b.lo + t.hi
    asm("v_pk_fma_f32 %0, %1, %2, %3 op_sel:[1,1,0] op_sel_hi:[1,0,1] neg_lo:[1,0,0]"
        : "=v"(r) : "v"(a), "v"(b), "v"(t));
    return r;
}

__device__ __forceinline__ f2 cadd(f2 a, f2 b) {
    f2 r; asm("v_pk_add_f32 %0, %1, %2" : "=v"(r) : "v"(a), "v"(b)); return r;
}
__device__ __forceinline__ f2 csub(f2 a, f2 b) {   // a - b
    f2 r;
    asm("v_pk_add_f32 %0, %1, %2 neg_lo:[0,1] neg_hi:[0,1]" : "=v"(r) : "v"(a), "v"(b));
    return r;
}
// r = s.lo * a (scalar-dup multiply; only s.lo is read)
__device__ __forceinline__ f2 smul(f2 s, f2 a) {
    f2 r;
    asm("v_pk_mul_f32 %0, %1, %2 op_sel_hi:[0,1]" : "=v"(r) : "v"(s), "v"(a));
    return r;
}
// r = (s.lo*a.lo, -s.lo*a.hi)   (for psi = rs * conj(f))
__device__ __forceinline__ f2 smulconj(f2 s, f2 a) {
    f2 r;
    asm("v_pk_mul_f32 %0, %1, %2 op_sel_hi:[0,1] neg_hi:[0,1]" : "=v"(r) : "v"(s), "v"(a));
    return r;
}
// r = s.lo * g + w   (scalar-dup FMA; only s.lo is read)
__device__ __forceinline__ f2 sfma(f2 s, f2 g, f2 w) {
    f2 r;
    asm("v_pk_fma_f32 %0, %1, %2, %3 op_sel_hi:[0,1,1]"
        : "=v"(r) : "v"(s), "v"(g), "v"(w));
    return r;
}

// ---- parallel precompute: tab[n] = (s, 0, s*Cr, s*Ci) -------------------
// s = LRW/(sum|u_n|^2+eps); C = sum conj(u_n)*u_{n+1}  (input-only)
__global__ void pre_tab(const float* __restrict__ xre,
                        const float* __restrict__ xim,
                        float4* __restrict__ tab, int ns) {
    int n = blockIdx.x * blockDim.x + threadIdx.x;
    if (n >= ns) return;
    const float* ar = xre + 4 * n;
    const float* ai = xim + 4 * n;
    float un = 0.f;
    #pragma unroll 8
    for (int k = 0; k < 64; ++k) un = fmaf(ar[k], ar[k], fmaf(ai[k], ai[k], un));
    float s = (1.0f / 64.0f) / (un + 1e-8f);
    float cr = 0.f, ci = 0.f;
    if (n + 1 < ns) {
        const float* br_ = ar + 4;
        const float* bi_ = ai + 4;
        #pragma unroll 8
        for (int k = 0; k < 64; ++k) {
            cr = fmaf(ar[k], br_[k], fmaf(ai[k], bi_[k], cr));
            ci = fmaf(ar[k], bi_[k], ci);
            ci = fmaf(-ai[k], br_[k], ci);
        }
    }
    tab[n] = make_float4(s, 0.f, s * cr, s * ci);
}

// ---- DDLMS scan: one wave64; packed complex; distance-3 prefetch --------
template<bool PRE>
__global__ __launch_bounds__(64, 1)
void ddlms_scan(const float* __restrict__ xre,
                const float* __restrict__ xim,
                const float4* __restrict__ tab,
                float* __restrict__ out) {
    const int l = (int)threadIdx.x;
    const int m = l & 31;
    const int half = l >> 5;

    constexpr float EPSv = 1e-8f;
    constexpr float LRW  = 1.0f / 64.0f;
    constexpr float LRF  = 1.0f / 128.0f;
    constexpr float LRB  = 1.0f / 2048.0f;
    const float B1 = 0.6324555320336759f;
    const float A1 = 0.31622776601683794f;
    const float A3 = 0.9486832980505138f;

    f2 wA = {0.f, 0.f}, wB = {0.f, 0.f};     // 2 taps/lane, (re,im) packed
    f2 ff2 = {1.f, 0.f};                     // f
    f2 bb  = {0.f, 0.f};                     // b
    f2 psi = {1.f, 0.f};                     // conj(f)/|f|
    f2 vv  = {0.f, 0.f};                     // v for upcoming step
    f2 ewP = {0.f, 0.f};                     // prev step's ew
    f2 sPv = {0.f, 0.f};                     // prev step's (s, 0) pair
    const f2 LRBD = {LRB, LRB};

    float2* __restrict__ o2 = reinterpret_cast<float2*>(out);
    const int NS = 99985;

    auto LOADU = [&](int nn, f2& a, f2& b_) {
        const float* pr = xre + 4 * nn;
        const float* pi = xim + 4 * nn;
        a.x = pr[m];      a.y = pi[m];
        b_.x = pr[m + 32]; b_.y = pi[m + 32];
    };
    auto LOADT = [&](int nn, float4& t) {
        if constexpr (PRE) t = tab[nn];
    };

    // 4 rotating u slots and 4 t slots
    f2 u0A, u0B, u1A, u1B, u2A, u2B, u3A, u3B;
    float4 t0 = {0,0,0,0}, t1 = {0,0,0,0}, t2 = {0,0,0,0}, t3 = {0,0,0,0};

    u3A = f2{0.f, 0.f}; u3B = f2{0.f, 0.f};  // uP for step 0 (sP=0)
    LOADU(0, u0A, u0B);
    LOADU(1, u1A, u1B);
    LOADU(2, u2A, u2B);
    LOADT(0, t0); LOADT(1, t1); LOADT(2, t2);

    auto STEP = [&](int n,
        f2& uPA, f2& uPB,          // slot (n-1)%4: read u_{n-1}, then prefetch u_{n+3}
        f2& uCA, f2& uCB,          // slot  n   %4 (non-PRE only)
        f2& uNA, f2& uNB,          // slot (n+1)%4
        float4& tC, float4& tF) {  // t slot n%4 ; t slot (n+3)%4

        // shadow: w += sP*(ewP (x) conj(uP))
        wA = sfma(sPv, cmulc(ewP, uPA), wA);
        wB = sfma(sPv, cmulc(ewP, uPB), wB);

        // distance-3 prefetch into the now-dead uP/tF slots
        {
            int nn = n + 3; if (nn > NS - 1) nn = NS - 1;
            LOADU(nn, uPA, uPB);
            LOADT(nn, tF);
        }

        // shadow: base_{n+1} = red(w_n * u_{n+1})
        f2 acc = cmul(wA, uNA);
        acc = cfma(wB, uNB, acc);
        f2 bas; bas.x = red32(acc.x); bas.y = red32(acc.y);

        // per-step scalars (s,0) pair and sC pair
        f2 sNv, sC;
        if constexpr (PRE) {
            sNv = f2{tC.x, tC.y};
            sC  = f2{tC.z, tC.w};
        } else {
            float uu = uCA.x * uCA.x; uu = fmaf(uCA.y, uCA.y, uu);
            uu = fmaf(uCB.x, uCB.x, uu); uu = fmaf(uCB.y, uCB.y, uu);
            float sN = LRW * __builtin_amdgcn_rcpf(red32(uu) + EPSv);
            float ccr = uCA.x * uNA.x; ccr = fmaf(uCA.y, uNA.y, ccr);
            ccr = fmaf(uCB.x, uNB.x, ccr); ccr = fmaf(uCB.y, uNB.y, ccr);
            float cci = uCA.x * uNA.y; cci = fmaf(-uCA.y, uNA.x, cci);
            cci = fmaf(uCB.x, uNB.y, cci); cci = fmaf(-uCB.y, uNB.x, cci);
            sNv = f2{sN, 0.f};
            sC  = f2{sN * red32(ccr), sN * red32(cci)};
        }

        // ---- critical chain ----
        f2 zz = cadd(cmul(vv, ff2), bb);            // z = v*f + b
        if (m == 0) o2[2 * n + half] = make_float2(zz.x, zz.y);

        float magr = (fabsf(zz.x) > B1) ? A3 : A1;  // slicer (scalar; tie->neg)
        float dr_  = (zz.x <= 0.f) ? -magr : magr;
        float magi = (fabsf(zz.y) > B1) ? A3 : A1;
        float di_  = (zz.y <= 0.f) ? -magi : magi;
        f2 dd; dd.x = dr_; dd.y = di_;

        f2 ee = csub(dd, zz);                       // e
        f2 db = csub(dd, bb);                       // d - b (old b)

        float v2 = fmaf(vv.x, vv.x, fmaf(vv.y, vv.y, EPSv));
        float rv = __builtin_amdgcn_rcpf(v2);
        f2 rvv; rvv.x = rv; rvv.y = rv;
        f2 gf = smul(rvv, cmulc(ee, vv));           // gf = e*conj(v)*rv
        float m2 = fmaf(gf.x, gf.x, gf.y * gf.y);
        float scf = fminf(1.f, 30.f * __builtin_amdgcn_rsqf(m2));  // m2=0 -> 1
        float tf = LRF * scf;
        f2 tfv; tfv.x = tf; tfv.y = tf;

        f2 ew = csub(cmul(db, psi), vv);            // e_w = db*psi - v

        vv = cadd(bas, cmul(ew, sC));               // v_{n+1} = bas + ew*sC

        ff2 = sfma(tfv, gf, ff2);                   // f += tf*gf
        bb  = sfma(LRBD, ee, bb);                   // b += LRB*e

        float ffn = fmaf(ff2.x, ff2.x, ff2.y * ff2.y);
        float rs = __builtin_amdgcn_rsqf(ffn);
        f2 rsv; rsv.x = rs; rsv.y = rs;
        psi = smulconj(rsv, ff2);                   // psi = rs*conj(f)

        ewP = ew; sPv = sNv;
    };

    int n = 0;
    for (int it = 0; it < 24996; ++it) {     // 4*24996 = 99984 steps
        STEP(n+0, u3A,u3B, u0A,u0B, u1A,u1B, t0, t3);
        STEP(n+1, u0A,u0B, u1A,u1B, u2A,u2B, t1, t0);
        STEP(n+2, u1A,u1B, u2A,u2B, u3A,u3B, t2, t1);
        STEP(n+3, u2A,u2B, u3A,u3B, u0A,u0B, t3, t2);
        n += 4;
    }
    // tail step 99984 (k=0 pattern; prefetch clamps to 99984)
    STEP(99984, u3A,u3B, u0A,u0B, u1A,u1B, t0, t3);
}

extern "C" void kernel_launch(void* const* d_in, const int* in_sizes, int n_in,
                              void* d_out, int out_size, void* d_ws, size_t ws_size,
                              hipStream_t stream) {
    const float* xre = (const float*)d_in[0];
    const float* xim = (const float*)d_in[1];
    float* out = (float*)d_out;
    const int NS = 99985;

    if (ws_size >= (size_t)NS * sizeof(float4)) {
        float4* tab = (float4*)d_ws;
        pre_tab<<<(NS + 255) / 256, 256, 0, stream>>>(xre, xim, tab, NS);
        ddlms_scan<true><<<1, 64, 0, stream>>>(xre, xim, tab, out);
    } else {
        ddlms_scan<false><<<1, 64, 0, stream>>>(xre, xim, nullptr, out);
    }
}